// Round 2
// baseline (11787.160 us; speedup 1.0000x reference)
//
#include <hip/hip_runtime.h>
#include <math.h>

#define BD 2
#define SD 1024
#define DDIM 1024
#define HH 16
#define LL 9
#define WW 1024
#define PP 128
#define VV 256
#define NN (BD*SD)

typedef __attribute__((ext_vector_type(8))) short short8;
typedef __attribute__((ext_vector_type(4))) float f32x4;

__device__ __forceinline__ float bf2f(unsigned int u) {
    return __uint_as_float((u & 0xffffu) << 16);
}
__device__ __forceinline__ unsigned short f2bf(float f) {
    unsigned int u = __float_as_uint(f);
    unsigned int r = (u + 0x7fffu + ((u >> 16) & 1u)) >> 16;
    return (unsigned short)r;
}

__device__ __forceinline__ float block_reduce_sum(float v, float* red) {
#pragma unroll
    for (int off = 32; off > 0; off >>= 1) v += __shfl_down(v, off);
    __syncthreads();
    if ((threadIdx.x & 63) == 0) red[threadIdx.x >> 6] = v;
    __syncthreads();
    return red[0] + red[1] + red[2] + red[3];
}
__device__ __forceinline__ float block_reduce_max(float v, float* red) {
#pragma unroll
    for (int off = 32; off > 0; off >>= 1) v = fmaxf(v, __shfl_down(v, off));
    __syncthreads();
    if ((threadIdx.x & 63) == 0) red[threadIdx.x >> 6] = v;
    __syncthreads();
    return fmaxf(fmaxf(red[0], red[1]), fmaxf(red[2], red[3]));
}

// ---------------- embed: x = byte_emb[tok] + pos_emb[s] (fp32) ----------------
__global__ __launch_bounds__(256) void embed_kernel(
    const int* __restrict__ seq, const float* __restrict__ bemb,
    const float* __restrict__ pemb, float* __restrict__ x)
{
    int i = blockIdx.x * 256 + threadIdx.x;
    if (i >= NN * DDIM) return;
    int n = i >> 10, d = i & 1023;
    int s = n & (SD - 1);
    int tok = seq[n];
    x[i] = bemb[tok * DDIM + d] + pemb[s * DDIM + d];
}

// ---------------- patch fp32 -> bf16 ----------------
__global__ __launch_bounds__(256) void cvt_bf16_kernel(
    const float* __restrict__ in, unsigned short* __restrict__ out, int n)
{
    int i = blockIdx.x * 256 + threadIdx.x;
    if (i < n) out[i] = f2bf(in[i]);
}

// ---------------- pidx = inclusive cumsum of patch_boundaries ----------------
__global__ void pidx_kernel(const int* __restrict__ pb, int* __restrict__ pidx)
{
    int b = threadIdx.x;
    if (b < BD) {
        int c = 0;
        for (int s = 0; s < SD; ++s) { c += pb[b * SD + s]; pidx[b * SD + s] = c; }
    }
}

// ---------------- LayerNorm: fp32 in -> bf16 out ----------------
__global__ __launch_bounds__(256) void ln_kernel(
    const float* __restrict__ x, const float* __restrict__ gg,
    const float* __restrict__ bb, unsigned short* __restrict__ out)
{
    __shared__ float red[4];
    const int row = blockIdx.x, tid = threadIdx.x;
    const float* xr = x + (size_t)row * DDIM;
    float v[4]; float s = 0.f, s2 = 0.f;
#pragma unroll
    for (int i = 0; i < 4; ++i) {
        float t = xr[tid + i * 256]; v[i] = t; s += t; s2 += t * t;
    }
    s = block_reduce_sum(s, red);
    __syncthreads();
    s2 = block_reduce_sum(s2, red);
    float mean = s * (1.f / DDIM);
    float var = s2 * (1.f / DDIM) - mean * mean;
    float rs = rsqrtf(var + 1e-5f);
    unsigned short* orow = out + (size_t)row * DDIM;
#pragma unroll
    for (int i = 0; i < 4; ++i) {
        int c = tid + i * 256;
        orow[c] = f2bf((v[i] - mean) * rs * gg[c] + bb[c]);
    }
}

// ---------------- GEMM: C[M,N] = A[M,K](bf16) @ B[N,K](fp32)^T + bias --------
// MODE 0: store fp32 to resid[M,N] (plain store)
// MODE 1: resid[M,N] (fp32) += val
// MODE 2: store bf16 gelu(val) to o0
// MODE 3: qkv scatter: which=col>>10 -> o{0,1,2}[((b*H+h)*seq+s)*64+d]
template<int MODE>
__global__ __launch_bounds__(256) void gemm_bt(
    const unsigned short* __restrict__ A, const float* __restrict__ B,
    const float* __restrict__ bias, float* __restrict__ resid,
    unsigned short* __restrict__ o0, unsigned short* __restrict__ o1,
    unsigned short* __restrict__ o2, int M, int N, int K, int seq)
{
    __shared__ __align__(16) unsigned short As[64 * 40];
    __shared__ __align__(16) unsigned short Bs[64 * 40];
    const int tid = threadIdx.x;
    const int m0 = blockIdx.y * 64, n0 = blockIdx.x * 64;
    const int w = tid >> 6, lane = tid & 63, quad = lane >> 4, mrow = lane & 15;
    f32x4 acc[4] = {{0,0,0,0},{0,0,0,0},{0,0,0,0},{0,0,0,0}};
    const int lr = tid >> 2, lc = (tid & 3) * 8;
    const uint4*  gA = (const uint4*)(A + (size_t)(m0 + lr) * K + lc);
    const float4* gB = (const float4*)(B + (size_t)(n0 + lr) * K + lc);

    for (int k0 = 0; k0 < K; k0 += 32) {
        __syncthreads();
        *(uint4*)&As[lr * 40 + lc] = gA[0];
        float4 b0 = gB[0], b1 = gB[1];
        short8 bv;
        bv[0] = (short)f2bf(b0.x); bv[1] = (short)f2bf(b0.y);
        bv[2] = (short)f2bf(b0.z); bv[3] = (short)f2bf(b0.w);
        bv[4] = (short)f2bf(b1.x); bv[5] = (short)f2bf(b1.y);
        bv[6] = (short)f2bf(b1.z); bv[7] = (short)f2bf(b1.w);
        *(short8*)&Bs[lr * 40 + lc] = bv;
        gA += 4; gB += 8;
        __syncthreads();
        short8 a = *(const short8*)&As[(w * 16 + mrow) * 40 + quad * 8];
#pragma unroll
        for (int t = 0; t < 4; ++t) {
            short8 bf = *(const short8*)&Bs[(t * 16 + mrow) * 40 + quad * 8];
            acc[t] = __builtin_amdgcn_mfma_f32_16x16x32_bf16(a, bf, acc[t], 0, 0, 0);
        }
    }

#pragma unroll
    for (int t = 0; t < 4; ++t) {
#pragma unroll
        for (int r = 0; r < 4; ++r) {
            int grow = m0 + w * 16 + quad * 4 + r;
            int gcol = n0 + t * 16 + mrow;
            float val = acc[t][r];
            if (bias) val += bias[gcol];
            if constexpr (MODE == 0) {
                resid[(size_t)grow * N + gcol] = val;
            } else if constexpr (MODE == 1) {
                resid[(size_t)grow * N + gcol] += val;
            } else if constexpr (MODE == 2) {
                float g = 0.5f * val * (1.0f + erff(val * 0.70710678118f));
                o0[(size_t)grow * N + gcol] = f2bf(g);
            } else {
                int which = gcol >> 10;
                int cD = gcol & 1023;
                int h = cD >> 6, d = cD & 63;
                int b = grow / seq, s = grow % seq;
                unsigned short* dst = (which == 0) ? o0 : ((which == 1) ? o1 : o2);
                dst[(((size_t)(b * HH + h)) * seq + s) * 64 + d] = f2bf(val);
            }
        }
    }
}

// ---------------- attention: block per (b,h,q), 2-pass softmax --------------
// Q:[B,H,Sq,64] K,V:[B,H,Sk,64] bf16; O:[B*Sq, Dm] bf16 concat-head
template<bool CAUSAL>
__global__ __launch_bounds__(256) void attn_kernel(
    const unsigned short* __restrict__ Q, const unsigned short* __restrict__ K,
    const unsigned short* __restrict__ V, unsigned short* __restrict__ O,
    const int* __restrict__ pidx, int Sq, int Sk, int Dm, float scale, int Wwin)
{
    const int b = blockIdx.z, h = blockIdx.y, qi = blockIdx.x;
    const int tid = threadIdx.x;
    __shared__ float qs[64];
    __shared__ float sc[1024];
    __shared__ float red[4];
    __shared__ float part[256];
    const size_t hbase = ((size_t)b * HH + h);
    const size_t qoff = (hbase * Sq + qi) * 64;
    if (tid < 64) qs[tid] = bf2f(Q[qoff + tid]);
    int jmin, jmax;
    if (CAUSAL) {
        jmin = qi - Wwin + 1; if (jmin < 0) jmin = 0;
        jmax = qi;
    } else {
        jmin = 0;
        int p = pidx[b * Sq + qi];
        jmax = (p < Sk - 1) ? p : (Sk - 1);
    }
    __syncthreads();

    float lmax = -3.0e38f;
    for (int j = jmin + tid; j <= jmax; j += 256) {
        const uint4* kp = (const uint4*)(K + (hbase * Sk + j) * 64);
        float s = 0.f;
#pragma unroll
        for (int g = 0; g < 8; ++g) {
            uint4 u = kp[g];
            s += qs[g*8+0] * bf2f(u.x) + qs[g*8+1] * bf2f(u.x >> 16)
               + qs[g*8+2] * bf2f(u.y) + qs[g*8+3] * bf2f(u.y >> 16)
               + qs[g*8+4] * bf2f(u.z) + qs[g*8+5] * bf2f(u.z >> 16)
               + qs[g*8+6] * bf2f(u.w) + qs[g*8+7] * bf2f(u.w >> 16);
        }
        s *= scale;
        sc[j] = s;
        lmax = fmaxf(lmax, s);
    }
    float m = block_reduce_max(lmax, red);
    __syncthreads();
    float lsum = 0.f;
    for (int j = jmin + tid; j <= jmax; j += 256) {
        float e = __expf(sc[j] - m);
        sc[j] = e;
        lsum += e;
    }
    float ssum = block_reduce_sum(lsum, red);
    __syncthreads();   // ensure all sc[] writes visible before PV pass
    float inv = 1.0f / ssum;

    const int d = tid & 63, p = tid >> 6;
    float acc = 0.f;
    for (int j = jmin + p; j <= jmax; j += 4) {
        acc += sc[j] * bf2f(V[(hbase * Sk + j) * 64 + d]);
    }
    part[tid] = acc;
    __syncthreads();
    if (tid < 64) {
        float o = (part[tid] + part[tid + 64] + part[tid + 128] + part[tid + 192]) * inv;
        O[((size_t)(b * Sq + qi)) * Dm + h * 64 + d] = f2bf(o);
    }
}

// ---------------------------------------------------------------------------
extern "C" void kernel_launch(void* const* d_in, const int* in_sizes, int n_in,
                              void* d_out, int out_size, void* d_ws, size_t ws_size,
                              hipStream_t stream)
{
    (void)in_sizes; (void)n_in; (void)out_size; (void)ws_size;
    const int*   byte_seq = (const int*)d_in[0];
    const float* patch    = (const float*)d_in[1];
    const int*   pbound   = (const int*)d_in[2];
    const float* byte_emb = (const float*)d_in[3];
    const float* pos_emb  = (const float*)d_in[4];
    const float* sa_in_w  = (const float*)d_in[5];
    const float* sa_in_b  = (const float*)d_in[6];
    const float* sa_out_w = (const float*)d_in[7];
    const float* sa_out_b = (const float*)d_in[8];
    const float* ca_in_w  = (const float*)d_in[9];
    const float* ca_in_b  = (const float*)d_in[10];
    const float* ca_out_w = (const float*)d_in[11];
    const float* ca_out_b = (const float*)d_in[12];
    const float* ffn_w1   = (const float*)d_in[13];
    const float* ffn_b1   = (const float*)d_in[14];
    const float* ffn_w2   = (const float*)d_in[15];
    const float* ffn_b2   = (const float*)d_in[16];
    const float* ln_g     = (const float*)d_in[17];
    const float* ln_b     = (const float*)d_in[18];
    const float* norm_g   = (const float*)d_in[19];
    const float* norm_b   = (const float*)d_in[20];
    const float* out_w    = (const float*)d_in[21];

    char* ws = (char*)d_ws;
    float*          x   = (float*)(ws + 0);                    //  8 MB fp32 residual
    unsigned short* h   = (unsigned short*)(ws + 8388608);     //  4 MB
    unsigned short* q   = (unsigned short*)(ws + 12582912);    //  4 MB
    unsigned short* k   = (unsigned short*)(ws + 16777216);    //  4 MB
    unsigned short* v   = (unsigned short*)(ws + 20971520);    //  4 MB
    unsigned short* aO  = (unsigned short*)(ws + 25165824);    //  4 MB
    unsigned short* u   = (unsigned short*)(ws + 12582912);    // 16 MB, aliases q/k/v/aO (dead by FFN)
    unsigned short* kca = (unsigned short*)(ws + 29360128);    // 512 KB
    unsigned short* vca = (unsigned short*)(ws + 29884416);    // 512 KB
    unsigned short* pp  = (unsigned short*)(ws + 30408704);    // 512 KB patch bf16
    int*            pidx = (int*)(ws + 30932992);              //   8 KB

    embed_kernel<<<(NN * DDIM + 255) / 256, 256, 0, stream>>>(byte_seq, byte_emb, pos_emb, x);
    cvt_bf16_kernel<<<(BD * PP * DDIM + 255) / 256, 256, 0, stream>>>(patch, pp, BD * PP * DDIM);
    pidx_kernel<<<1, 64, 0, stream>>>(pbound, pidx);

    for (int l = 0; l < LL; ++l) {
        const float* lg = ln_g + (size_t)(l * 3) * DDIM;
        const float* lb = ln_b + (size_t)(l * 3) * DDIM;
        // ---- self-attention block ----
        ln_kernel<<<NN, 256, 0, stream>>>(x, lg, lb, h);
        gemm_bt<3><<<dim3(3 * DDIM / 64, NN / 64), 256, 0, stream>>>(
            h, sa_in_w + (size_t)l * 3 * DDIM * DDIM, sa_in_b + (size_t)l * 3 * DDIM,
            nullptr, q, k, v, NN, 3 * DDIM, DDIM, SD);
        attn_kernel<true><<<dim3(SD, HH, BD), 256, 0, stream>>>(
            q, k, v, aO, nullptr, SD, SD, DDIM, 0.125f, WW);
        gemm_bt<1><<<dim3(DDIM / 64, NN / 64), 256, 0, stream>>>(
            aO, sa_out_w + (size_t)l * DDIM * DDIM, sa_out_b + (size_t)l * DDIM,
            x, nullptr, nullptr, nullptr, NN, DDIM, DDIM, 0);
        // ---- cross-attention block ----
        ln_kernel<<<NN, 256, 0, stream>>>(x, lg + DDIM, lb + DDIM, h);
        gemm_bt<3><<<dim3(DDIM / 64, NN / 64), 256, 0, stream>>>(
            h, ca_in_w + (size_t)l * 3 * DDIM * DDIM, ca_in_b + (size_t)l * 3 * DDIM,
            nullptr, q, nullptr, nullptr, NN, DDIM, DDIM, SD);
        gemm_bt<3><<<dim3(2 * DDIM / 64, (BD * PP) / 64), 256, 0, stream>>>(
            pp, ca_in_w + (size_t)l * 3 * DDIM * DDIM + (size_t)DDIM * DDIM,
            ca_in_b + (size_t)l * 3 * DDIM + DDIM,
            nullptr, kca, vca, nullptr, BD * PP, 2 * DDIM, DDIM, PP);
        attn_kernel<false><<<dim3(SD, HH, BD), 256, 0, stream>>>(
            q, kca, vca, aO, pidx, SD, PP, DDIM, 0.125f, 0);
        gemm_bt<1><<<dim3(DDIM / 64, NN / 64), 256, 0, stream>>>(
            aO, ca_out_w + (size_t)l * DDIM * DDIM, ca_out_b + (size_t)l * DDIM,
            x, nullptr, nullptr, nullptr, NN, DDIM, DDIM, 0);
        // ---- FFN block ----
        ln_kernel<<<NN, 256, 0, stream>>>(x, lg + 2 * DDIM, lb + 2 * DDIM, h);
        gemm_bt<2><<<dim3(4 * DDIM / 64, NN / 64), 256, 0, stream>>>(
            h, ffn_w1 + (size_t)l * 4 * DDIM * DDIM, ffn_b1 + (size_t)l * 4 * DDIM,
            nullptr, u, nullptr, nullptr, NN, 4 * DDIM, DDIM, 0);
        gemm_bt<1><<<dim3(DDIM / 64, NN / 64), 256, 0, stream>>>(
            u, ffn_w2 + (size_t)l * DDIM * 4 * DDIM, ffn_b2 + (size_t)l * DDIM,
            x, nullptr, nullptr, nullptr, NN, DDIM, 4 * DDIM, 0);
    }
    ln_kernel<<<NN, 256, 0, stream>>>(x, norm_g, norm_b, h);
    gemm_bt<0><<<dim3(VV / 64, NN / 64), 256, 0, stream>>>(
        h, out_w, nullptr, (float*)d_out, nullptr, nullptr, nullptr,
        NN, VV, DDIM, 0);
}